// Round 6
// baseline (148.671 us; speedup 1.0000x reference)
//
#include <hip/hip_runtime.h>

typedef float f4 __attribute__((ext_vector_type(4)));

#define BB 1024
#define SS 192
#define DD 512
#define NUM_LAYERS 3
#define LN_EPS 1e-5f

// Merged prep:
//  blocks [0, SS)      : add_tab[pos] = item_pos[pos/3] + layer[pos%3] + decay[pos/3]
//  blocks [SS, SS+256) : start[b] via ballot; start=SS if row has no content
__global__ __launch_bounds__(256) void prep_kernel(
    const int* __restrict__ mask,
    const float* __restrict__ item_pos,
    const float* __restrict__ layer_emb,
    const float* __restrict__ decay,
    float* __restrict__ add_tab,
    int* __restrict__ start)
{
    if (blockIdx.x < SS) {
        const int p = blockIdx.x;
        const int t = threadIdx.x;
        if (t < DD / 4) {
            const int item = p / NUM_LAYERS;
            const int layer = p - item * NUM_LAYERS;
            const f4 iv = reinterpret_cast<const f4*>(item_pos + item * DD)[t];
            const f4 lv = reinterpret_cast<const f4*>(layer_emb + layer * DD)[t];
            const f4 dv = reinterpret_cast<const f4*>(decay + item * DD)[t];
            reinterpret_cast<f4*>(add_tab + p * DD)[t] = iv + lv + dv;
        }
    } else {
        const int b = (blockIdx.x - SS) * 4 + (threadIdx.x >> 6);
        const int lane = threadIdx.x & 63;
        if (b < BB) {
            const int* m = mask + b * SS;
            const unsigned long long b0 = __ballot(m[lane] > 0);
            const unsigned long long b1 = __ballot(m[lane + 64] > 0);
            const unsigned long long b2 = __ballot(m[lane + 128] > 0);
            int idx;
            if (b0)      idx = __ffsll(b0) - 1;
            else if (b1) idx = 64 + __ffsll(b1) - 1;
            else if (b2) idx = 128 + __ffsll(b2) - 1;
            else         idx = SS;
            if (lane == 0) start[b] = idx;
        }
    }
}

// DPP-based wave64 all-reduce (sum): 4 VALU-latency DPP levels + xor16 swizzle
// + cross-32 bpermute. No lgkm chain of 6 ds ops like shfl_xor butterfly.
__device__ __forceinline__ float wave_allreduce(float v, int xaddr32) {
    v += __uint_as_float((unsigned)__builtin_amdgcn_update_dpp(
            0, (int)__float_as_uint(v), 0xB1, 0xF, 0xF, true));   // xor1
    v += __uint_as_float((unsigned)__builtin_amdgcn_update_dpp(
            0, (int)__float_as_uint(v), 0x4E, 0xF, 0xF, true));   // xor2
    v += __uint_as_float((unsigned)__builtin_amdgcn_update_dpp(
            0, (int)__float_as_uint(v), 0x141, 0xF, 0xF, true));  // row_half_mirror
    v += __uint_as_float((unsigned)__builtin_amdgcn_update_dpp(
            0, (int)__float_as_uint(v), 0x140, 0xF, 0xF, true));  // row_mirror
    v += __uint_as_float((unsigned)__builtin_amdgcn_ds_swizzle(
            (int)__float_as_uint(v), 0x401f));                    // xor16
    v += __uint_as_float((unsigned)__builtin_amdgcn_ds_bpermute(
            xaddr32, (int)__float_as_uint(v)));                   // xor32
    return v;
}

// Two blocks per batch row b. Phase 1: dense fire-and-forget zero-store of the
// padded prefix (pure write burst, overlaps phase-2 load latency). Phase 2:
// 4 waves per block process content rows [st, 192) -- no per-row branch, no
// mask/start loads, long contiguous read/write runs per b.
__global__ __launch_bounds__(256) void fused_kernel(
    const float* __restrict__ tok,
    const float* __restrict__ add_tab,
    const float* __restrict__ lnw,
    const float* __restrict__ lnb,
    const int* __restrict__ start,
    float* __restrict__ out)
{
    const int b = blockIdx.x >> 1;
    const int half = blockIdx.x & 1;
    const int tid = threadIdx.x;
    const int wid = tid >> 6;
    const int lane = tid & 63;
    const int l0 = lane;
    const int l1 = lane + 64;
    const int xaddr32 = (lane ^ 32) << 2;

    const int st = start[b];                      // scalar (block-uniform), once

    // LN params: issue early, in flight during phase 1
    const f4 w0 = reinterpret_cast<const f4*>(lnw)[l0];
    const f4 w1 = reinterpret_cast<const f4*>(lnw)[l1];
    const f4 c0 = reinterpret_cast<const f4*>(lnb)[l0];
    const f4 c1 = reinterpret_cast<const f4*>(lnb)[l1];

    float* const obase = out + (size_t)b * SS * DD;

    // ---- phase 1: zero padded prefix [0, st*DD) floats (this block's half) ----
    {
        f4* o4 = reinterpret_cast<f4*>(obase);
        const int nf4 = st * (DD / 4);
        const f4 z = {0.f, 0.f, 0.f, 0.f};
        for (int i = half * 256 + tid; i < nf4; i += 512)
            o4[i] = z;                            // independent stores, no waits
    }

    // ---- phase 2: content rows st + j, st + j + 8, ... ----
    const int j = half * 4 + wid;                 // 0..7 (8 waves per b)

    #pragma unroll 1
    for (int s = st + j; s < SS; s += 8) {
        const int pos = s - st;                   // 0..191

        const f4* x4 = reinterpret_cast<const f4*>(tok + (size_t)b * SS * DD + s * DD);
        const f4 xv0 = x4[l0];
        const f4 xv1 = x4[l1];

        const f4* a4 = reinterpret_cast<const f4*>(add_tab + pos * DD);
        const f4 y0 = xv0 + a4[l0];
        const f4 y1 = xv1 + a4[l1];

        float sum = (y0.x + y0.y) + (y0.z + y0.w)
                  + (y1.x + y1.y) + (y1.z + y1.w);
        const f4 q0 = y0 * y0;
        const f4 q1 = y1 * y1;
        float sq = (q0.x + q0.y) + (q0.z + q0.w)
                 + (q1.x + q1.y) + (q1.z + q1.w);

        sum = wave_allreduce(sum, xaddr32);
        sq  = wave_allreduce(sq, xaddr32);

        const float mu  = sum * (1.0f / DD);
        const float var = sq * (1.0f / DD) - mu * mu;
        const float inv = rsqrtf(var + LN_EPS);

        f4* o4 = reinterpret_cast<f4*>(obase + s * DD);
        o4[l0] = (y0 - mu) * inv * w0 + c0;
        o4[l1] = (y1 - mu) * inv * w1 + c1;
    }
}

extern "C" void kernel_launch(void* const* d_in, const int* in_sizes, int n_in,
                              void* d_out, int out_size, void* d_ws, size_t ws_size,
                              hipStream_t stream) {
    const float* tok       = (const float*)d_in[0];   // (B,S,D)
    const int*   mask      = (const int*)d_in[1];     // (B,S)
    const float* item_pos  = (const float*)d_in[2];   // (64,D)
    const float* layer_emb = (const float*)d_in[3];   // (3,D)
    const float* decay     = (const float*)d_in[4];   // (64,D)
    const float* lnw       = (const float*)d_in[5];   // (D,)
    const float* lnb       = (const float*)d_in[6];   // (D,)
    float* out = (float*)d_out;

    // workspace layout: [ add_tab: SS*DD floats ][ start: BB ints ]
    float* add_tab = (float*)d_ws;
    int* start = (int*)((char*)d_ws + (size_t)SS * DD * sizeof(float));

    prep_kernel<<<SS + 256, 256, 0, stream>>>(mask, item_pos, layer_emb, decay,
                                              add_tab, start);
    fused_kernel<<<BB * 2, 256, 0, stream>>>(tok, add_tab, lnw, lnb, start, out);
}